// Round 23
// baseline (272.851 us; speedup 1.0000x reference)
//
#include <hip/hip_runtime.h>
#include <hip/hip_bf16.h>
#include <hip/hip_fp8.h>

#define NN   100000
#define NE   1600000
#define NBK  196      // ceil(NN/512) buckets
#define BSH  9        // 512 nodes per bucket
#define EPB  8192     // edges per scatter block
#define CAP  9216     // padded capacity per bucket (mean 8163 + ~11 sigma)
#define PREPB 13012   // prep blocks in mega kernel: 512 weight + 12500 x-convert

typedef __attribute__((ext_vector_type(8))) short short8;
typedef __attribute__((ext_vector_type(4))) float f32x4;
typedef __attribute__((address_space(3))) uint  lds_uint;
typedef __attribute__((address_space(1))) const uint glb_uint;

__device__ __forceinline__ ushort f2bf(float f) {
    union { float f; uint u; } v; v.f = f;
    uint u = v.u;
    return (ushort)((u + 0x7FFFu + ((u >> 16) & 1u)) >> 16);
}
__device__ __forceinline__ float bf2f(uint b) {
    union { uint u; float f; } v; v.u = b << 16;
    return v.f;
}
__device__ __forceinline__ float fp8f(uint byte) {
    __hip_fp8_e4m3 t; t.__x = (__hip_fp8_storage_t)(byte & 0xffu);
    return (float)t;
}
__device__ __forceinline__ uint f2fp8(float f) {
    __hip_fp8_e4m3 t(f);
    return (uint)t.__x;
}
// XOR-swizzle for 512B-stride LDS rows (guide G4) — used for h buffer only
__device__ __forceinline__ int swz(int off) { return off ^ (((off >> 9) & 7) << 4); }

// async global->LDS copy of a 32KB fragment-major chunk (2048 x 16B)
__device__ __forceinline__ void stageB(const ushort* __restrict__ W, char* Bs,
                                       int wave, int lane) {
#pragma unroll
    for (int k = 0; k < 8; ++k) {
        int base = k * 256 + wave * 64;          // 16B-unit index, wave-uniform
        __builtin_amdgcn_global_load_lds(
            (glb_uint*)(W + (size_t)(base + lane) * 8),
            (lds_uint*)(Bs + base * 16), 16, 0, 0);
    }
}

// ---- mega kernel: prep (weights + x convert) blocks || bucket scatter blocks
// bcursor must be ZEROED before launch (hipMemsetAsync); scatter reservations
// are relative: global run base = b*CAP + atomicAdd(&bcursor[b], v).
__global__ __launch_bounds__(256) void prep_scatter(const float* __restrict__ W1l,
                                                    const float* __restrict__ W1r,
                                                    const float* __restrict__ Wlin,
                                                    const float* __restrict__ W2l,
                                                    const float* __restrict__ W2r,
                                                    const float* __restrict__ x,
                                                    const int* __restrict__ src,
                                                    const int* __restrict__ tgt,
                                                    ushort* __restrict__ Wcat1,
                                                    ushort* __restrict__ Wlinb,
                                                    ushort* __restrict__ Wcat2,
                                                    ushort* __restrict__ xbf,
                                                    uchar* __restrict__ x8,
                                                    int* __restrict__ bcursor,
                                                    uint* __restrict__ brec) {
    __shared__ int lh[NBK + 1];
    __shared__ int lcur[NBK];
    __shared__ int lbase[NBK];
    __shared__ uint lrec[EPB];
    __shared__ int ws[4];
    int b = blockIdx.x, tid = threadIdx.x;
    if (b < PREPB) {
        if (b < 512) {
            int i = b * 256 + tid;
            if (i < 65536) {               // Wcat1: 4 chunks (256 outputs, K=256)
                int e = i & 7, d = (i >> 3) & 63, g = (i >> 9) & 31, ch = i >> 14;
                int col = d & 15, kg = d >> 4, ks = g & 7, nt = g >> 3;
                int row = ch * 64 + nt * 16 + col;
                int k = ks * 32 + kg * 8 + e;
                float v = (k < 128) ? W1l[row * 128 + k] : W1r[row * 128 + k - 128];
                Wcat1[i] = f2bf(v);
            } else if (i < 98304) {        // Wlin: 2 chunks
                int j = i - 65536;
                int e = j & 7, d = (j >> 3) & 63, g = (j >> 9) & 31, ch = j >> 14;
                int col = d & 15, kg = d >> 4, ks = g & 7, nt = g >> 3;
                int row = ch * 64 + nt * 16 + col;
                int k = ks * 32 + kg * 8 + e;
                Wlinb[j] = f2bf(Wlin[row * 256 + k]);
            } else {                       // Wcat2: 2 chunks
                int j = i - 98304;
                int e = j & 7, d = (j >> 3) & 63, g = (j >> 9) & 31, ch = j >> 14;
                int col = d & 15, kg = d >> 4, ks = g & 7, nt = g >> 3;
                int row = ch * 64 + nt * 16 + col;
                int k = ks * 32 + kg * 8 + e;
                float v = (k < 128) ? W2l[row * 128 + k] : W2r[row * 128 + k - 128];
                Wcat2[j] = f2bf(v);
            }
        } else {
            int i = (b - 512) * 256 + tid;   // over NN*128/4 = 3.2M float4
            float4 v = ((const float4*)x)[i];
            ushort4 p;
            p.x = f2bf(v.x); p.y = f2bf(v.y); p.z = f2bf(v.z); p.w = f2bf(v.w);
            ((ushort4*)xbf)[i] = p;
            uint q = f2fp8(v.x) | (f2fp8(v.y) << 8) | (f2fp8(v.z) << 16) | (f2fp8(v.w) << 24);
            ((uint*)x8)[i] = q;
        }
        return;
    }
    // -------- scatter block --------
    int sb = b - PREPB;
    for (int i = tid; i < NBK; i += 256) lh[i] = 0;
    __syncthreads();
    int base4 = sb * (EPB / 4);
#pragma unroll
    for (int k = 0; k < 8; ++k) {
        int i4 = base4 + k * 256 + tid;
        if (i4 < NE / 4) {
            int4 t = ((const int4*)tgt)[i4];
            atomicAdd(&lh[t.x >> BSH], 1);
            atomicAdd(&lh[t.y >> BSH], 1);
            atomicAdd(&lh[t.z >> BSH], 1);
            atomicAdd(&lh[t.w >> BSH], 1);
        }
    }
    __syncthreads();
    int v = (tid < NBK) ? lh[tid] : 0;
    int lane = tid & 63, wid = tid >> 6;
    int inc = v;
#pragma unroll
    for (int off = 1; off < 64; off <<= 1) {
        int u = __shfl_up(inc, off);
        if (lane >= off) inc += u;
    }
    if (lane == 63) ws[wid] = inc;
    __syncthreads();
    int woff = 0;
    for (int w = 0; w < wid; ++w) woff += ws[w];
    int ex = woff + inc - v;
    int nval = min(EPB, NE - sb * EPB);
    if (tid < NBK) {
        lh[tid] = ex;
        lcur[tid] = ex;
        lbase[tid] = tid * CAP + (v ? atomicAdd(&bcursor[tid], v) : 0);
    }
    if (tid == 0) lh[NBK] = nval;
    __syncthreads();
#pragma unroll
    for (int k = 0; k < 8; ++k) {
        int i4 = base4 + k * 256 + tid;
        if (i4 < NE / 4) {
            int4 t = ((const int4*)tgt)[i4];
            int4 s = ((const int4*)src)[i4];
            int p;
            p = atomicAdd(&lcur[t.x >> BSH], 1); lrec[p] = ((uint)s.x << BSH) | (uint)(t.x & 511);
            p = atomicAdd(&lcur[t.y >> BSH], 1); lrec[p] = ((uint)s.y << BSH) | (uint)(t.y & 511);
            p = atomicAdd(&lcur[t.z >> BSH], 1); lrec[p] = ((uint)s.z << BSH) | (uint)(t.z & 511);
            p = atomicAdd(&lcur[t.w >> BSH], 1); lrec[p] = ((uint)s.w << BSH) | (uint)(t.w & 511);
        }
    }
    __syncthreads();
    // write-out: contiguous 32-elem chunk per thread, monotone bucket pointer
    {
        int i0 = tid * 32;
        int lo = 0, hi = NBK;
        while (hi - lo > 1) { int mid = (lo + hi) >> 1; if (lh[mid] <= i0) lo = mid; else hi = mid; }
#pragma unroll 4
        for (int k = 0; k < 32; ++k) {
            int i = i0 + k;
            if (i >= nval) break;
            while (lh[lo + 1] <= i) ++lo;
            brec[lbase[lo] + (i - lh[lo])] = lrec[i];
        }
    }
}

// ------- bucket -> CSR (padded regions; bcursor now holds COUNTS) -------
__global__ __launch_bounds__(256) void bucket_to_csr(const uint* __restrict__ brec,
                                                     const int* __restrict__ bcursor,
                                                     int* __restrict__ rowstart,
                                                     int* __restrict__ rowend,
                                                     int* __restrict__ sortedSrc) {
    __shared__ int cnt[512];
    __shared__ int cur[512];
    __shared__ int srt[CAP];
    __shared__ int ws[4];
    int b = blockIdx.x;
    int beg = b * CAP;
    int len = min(bcursor[b], CAP);
    int end = beg + len;
    int n0 = b << BSH;
    int ncnt = min(512, NN - n0);
    int tid = threadIdx.x;
    cnt[tid] = 0; cnt[tid + 256] = 0;
    __syncthreads();
    for (int i = beg + tid; i < end; i += 256)
        atomicAdd(&cnt[brec[i] & 511u], 1);
    __syncthreads();
    int c0 = cnt[2 * tid], c1 = cnt[2 * tid + 1];
    int s = c0 + c1;
    int lane = tid & 63, wid = tid >> 6;
    int inc = s;
#pragma unroll
    for (int off = 1; off < 64; off <<= 1) {
        int u = __shfl_up(inc, off);
        if (lane >= off) inc += u;
    }
    if (lane == 63) ws[wid] = inc;
    __syncthreads();
    int woff = 0;
    for (int w = 0; w < wid; ++w) woff += ws[w];
    int ex = woff + inc - s;
    cur[2 * tid] = ex; cur[2 * tid + 1] = ex + c0;
    if (2 * tid < ncnt) {
        rowstart[n0 + 2 * tid] = beg + ex;
        rowend[n0 + 2 * tid]   = beg + ex + c0;
    }
    if (2 * tid + 1 < ncnt) {
        rowstart[n0 + 2 * tid + 1] = beg + ex + c0;
        rowend[n0 + 2 * tid + 1]   = beg + ex + c0 + c1;
    }
    __syncthreads();
    for (int i = beg + tid; i < end; i += 256) {
        uint r = brec[i];
        int p = atomicAdd(&cur[r & 511u], 1);
        srt[p] = (int)(r >> BSH);
    }
    __syncthreads();
    for (int i = tid; i < len; i += 256)
        sortedSrc[beg + i] = srt[i];
}

// --- gather mean (fp8): wave/node, quarter-wave/edge, 8B/lane, unroll-4 ---
__global__ __launch_bounds__(256) void gather_mean8(const uchar* __restrict__ t8,
                                                    const int* __restrict__ rowstart,
                                                    const int* __restrict__ rowend,
                                                    const int* __restrict__ sortedSrc,
                                                    ushort* __restrict__ mean) {
    int node = blockIdx.x * 4 + (threadIdx.x >> 6);
    if (node >= NN) return;
    int lane = threadIdx.x & 63;
    int q = lane >> 4, l = lane & 15;
    int beg = rowstart[node], end = rowend[node];
    float a0 = 0.f, a1 = 0.f, a2 = 0.f, a3 = 0.f;
    float a4 = 0.f, a5 = 0.f, a6 = 0.f, a7 = 0.f;
    float b0 = 0.f, b1 = 0.f, b2 = 0.f, b3 = 0.f;
    float b4 = 0.f, b5 = 0.f, b6 = 0.f, b7 = 0.f;
#define ACCA(v) { a0 += fp8f(v.x);       a1 += fp8f(v.x >> 8); \
                  a2 += fp8f(v.x >> 16); a3 += fp8f(v.x >> 24); \
                  a4 += fp8f(v.y);       a5 += fp8f(v.y >> 8); \
                  a6 += fp8f(v.y >> 16); a7 += fp8f(v.y >> 24); }
#define ACCB(v) { b0 += fp8f(v.x);       b1 += fp8f(v.x >> 8); \
                  b2 += fp8f(v.x >> 16); b3 += fp8f(v.x >> 24); \
                  b4 += fp8f(v.y);       b5 += fp8f(v.y >> 8); \
                  b6 += fp8f(v.y >> 16); b7 += fp8f(v.y >> 24); }
    int i = beg + q;
    for (; i + 12 < end; i += 16) {
        int s0 = sortedSrc[i];
        int s1 = sortedSrc[i + 4];
        int s2 = sortedSrc[i + 8];
        int s3 = sortedSrc[i + 12];
        uint2 v0 = *(const uint2*)&t8[(size_t)s0 * 128 + l * 8];
        uint2 v1 = *(const uint2*)&t8[(size_t)s1 * 128 + l * 8];
        uint2 v2 = *(const uint2*)&t8[(size_t)s2 * 128 + l * 8];
        uint2 v3 = *(const uint2*)&t8[(size_t)s3 * 128 + l * 8];
        ACCA(v0) ACCB(v1) ACCA(v2) ACCB(v3)
    }
    for (; i < end; i += 4) {
        int s0 = sortedSrc[i];
        uint2 v0 = *(const uint2*)&t8[(size_t)s0 * 128 + l * 8];
        ACCA(v0)
    }
#undef ACCA
#undef ACCB
    a0 += b0; a1 += b1; a2 += b2; a3 += b3;
    a4 += b4; a5 += b5; a6 += b6; a7 += b7;
#define CMB(a) a += __shfl_xor(a, 32); a += __shfl_xor(a, 16);
    CMB(a0) CMB(a1) CMB(a2) CMB(a3) CMB(a4) CMB(a5) CMB(a6) CMB(a7)
#undef CMB
    if (lane < 16) {
        float id = 1.0f / fmaxf((float)(end - beg), 1.0f);
        ushort p[8];
        p[0] = f2bf(a0 * id); p[1] = f2bf(a1 * id);
        p[2] = f2bf(a2 * id); p[3] = f2bf(a3 * id);
        p[4] = f2bf(a4 * id); p[5] = f2bf(a5 * id);
        p[6] = f2bf(a6 * id); p[7] = f2bf(a7 * id);
        *(uint4*)&mean[(size_t)node * 128 + l * 8] = *(uint4*)p;
    }
}

// ---------------- hr bf16 -> fp8 (gather table only) ----------------
__global__ __launch_bounds__(256) void cvt8(const ushort* __restrict__ hr,
                                            uchar* __restrict__ hr8) {
    int i = blockIdx.x * 256 + threadIdx.x;   // over NN*128/8
    uint4 v = ((const uint4*)hr)[i];
    uint lo = f2fp8(bf2f(v.x & 0xffffu)) | (f2fp8(bf2f(v.x >> 16)) << 8) |
              (f2fp8(bf2f(v.y & 0xffffu)) << 16) | (f2fp8(bf2f(v.y >> 16)) << 24);
    uint hi = f2fp8(bf2f(v.z & 0xffffu)) | (f2fp8(bf2f(v.z >> 16)) << 8) |
              (f2fp8(bf2f(v.w & 0xffffu)) << 16) | (f2fp8(bf2f(v.w >> 16)) << 24);
    uint2 o; o.x = lo; o.y = hi;
    ((uint2*)hr8)[i] = o;
}

// --- conv1+linear fused: direct-global A, fragment-major B (gll),
//     As (32KB) used only for the h transpose; writes hr (bf16) ---
__global__ __launch_bounds__(256) void conv1lin_mfma(const ushort* __restrict__ mean,
                                                     const ushort* __restrict__ xbf,
                                                     const ushort* __restrict__ Wcat,
                                                     const float* __restrict__ bias1,
                                                     const ushort* __restrict__ Wlin,
                                                     const float* __restrict__ blin,
                                                     ushort* __restrict__ hr) {
    __shared__ char As[64 * 512];   // h buffer (swz layout)
    __shared__ char Bs[64 * 512];   // fragment-major weight chunk (32KB)
    int m0 = blockIdx.x * 64;
    int tid = threadIdx.x;
    int lane = tid & 63, wave = tid >> 6;
    int col = lane & 15, kg = lane >> 4;
    int mym = wave * 16 + col;
    int mm = min(m0 + mym, NN - 1);
    stageB(Wcat, Bs, wave, lane);
    short8 a[8];
#pragma unroll
    for (int ks = 0; ks < 4; ++ks)
        a[ks] = *(const short8*)&mean[(size_t)mm * 128 + ks * 32 + kg * 8];
#pragma unroll
    for (int ks = 4; ks < 8; ++ks)
        a[ks] = *(const short8*)&xbf[(size_t)mm * 128 + (ks - 4) * 32 + kg * 8];
    __syncthreads();                 // drains chunk-0 DMA + a-loads

    f32x4 acc[16];
    for (int ch = 0; ch < 4; ++ch) {       // 64-output fragment-major chunks
        if (ch) {
            __syncthreads();               // prior bq reads done before restage
            stageB(Wcat + (size_t)ch * 16384, Bs, wave, lane);
            __syncthreads();               // drain DMA
        }
#pragma unroll
        for (int nt = 0; nt < 4; ++nt) {
            f32x4 c = {0.f, 0.f, 0.f, 0.f};
#pragma unroll
            for (int ks = 0; ks < 8; ++ks)
                c = __builtin_amdgcn_mfma_f32_16x16x32_bf16(
                    a[ks], *(const short8*)(Bs + ((nt * 8 + ks) * 64 + lane) * 16), c, 0, 0, 0);
            acc[ch * 4 + nt] = c;
        }
    }
    // bias + l2norm  (chan for acc[i] = i*16 + col)
    float ssq[4] = {0.f, 0.f, 0.f, 0.f};
#pragma unroll
    for (int i = 0; i < 16; ++i) {
        float b = bias1[i * 16 + col];
#pragma unroll
        for (int r = 0; r < 4; ++r) {
            acc[i][r] += b;
            ssq[r] += acc[i][r] * acc[i][r];
        }
    }
#pragma unroll
    for (int off = 1; off < 16; off <<= 1)
#pragma unroll
        for (int r = 0; r < 4; ++r) ssq[r] += __shfl_xor(ssq[r], off);
    float rn[4];
#pragma unroll
    for (int r = 0; r < 4; ++r) rn[r] = 1.0f / fmaxf(sqrtf(ssq[r]), 1e-12f);
    // write normalized h (bf16) into As (own wave's rows only)
#pragma unroll
    for (int i = 0; i < 16; ++i) {
        int chan = i * 16 + col;
#pragma unroll
        for (int r = 0; r < 4; ++r)
            *(ushort*)(As + swz((wave * 16 + kg * 4 + r) * 512 + chan * 2)) = f2bf(acc[i][r] * rn[r]);
    }
    // second GEMM: hr = relu(h @ Wlin^T + blin); a2 rows self-owned (wave-local)
    short8 a2[8];
#pragma unroll
    for (int ks = 0; ks < 8; ++ks)
        a2[ks] = *(const short8*)(As + swz(mym * 512 + (ks * 32 + kg * 8) * 2));
    f32x4 acc2[8];
    for (int lc = 0; lc < 2; ++lc) {
        __syncthreads();                   // conv bq / prior reads done before restage
        stageB(Wlin + (size_t)lc * 16384, Bs, wave, lane);
        __syncthreads();
#pragma unroll
        for (int nt = 0; nt < 4; ++nt) {
            f32x4 c = {0.f, 0.f, 0.f, 0.f};
#pragma unroll
            for (int ks = 0; ks < 8; ++ks)
                c = __builtin_amdgcn_mfma_f32_16x16x32_bf16(
                    a2[ks], *(const short8*)(Bs + ((nt * 8 + ks) * 64 + lane) * 16), c, 0, 0, 0);
            acc2[lc * 4 + nt] = c;
        }
    }
#pragma unroll
    for (int i = 0; i < 8; ++i) {
        int chan = i * 16 + col;
        float b = blin[chan];
#pragma unroll
        for (int r = 0; r < 4; ++r) {
            int node = m0 + wave * 16 + kg * 4 + r;
            if (node < NN)
                hr[(size_t)node * 128 + chan] = f2bf(fmaxf(acc2[i][r] + b, 0.f));
        }
    }
}

// --- conv2 + linear2 + softmax: direct-global A (self-term bf16 from hr),
//     Bs-only LDS (32KB) ---
__global__ __launch_bounds__(256) void conv2_mfma(const ushort* __restrict__ mean,
                                                  const ushort* __restrict__ hr,
                                                  const ushort* __restrict__ Wcat,
                                                  const float* __restrict__ bias,
                                                  const float* __restrict__ Wlin2,
                                                  const float* __restrict__ blin2,
                                                  float* __restrict__ probs,
                                                  float* __restrict__ yout) {
    __shared__ char Bs[64 * 512];   // only LDS: 32KB weight chunk
    int m0 = blockIdx.x * 64;
    int tid = threadIdx.x;
    int lane = tid & 63, wave = tid >> 6;
    int col = lane & 15, kg = lane >> 4;
    int mym = wave * 16 + col;
    int mm = min(m0 + mym, NN - 1);
    stageB(Wcat, Bs, wave, lane);
    short8 a[8];
#pragma unroll
    for (int ks = 0; ks < 4; ++ks)
        a[ks] = *(const short8*)&mean[(size_t)mm * 128 + ks * 32 + kg * 8];
#pragma unroll
    for (int ks = 4; ks < 8; ++ks)
        a[ks] = *(const short8*)&hr[(size_t)mm * 128 + (ks - 4) * 32 + kg * 8];
    __syncthreads();

    f32x4 acc[8];
    for (int ch = 0; ch < 2; ++ch) {
        if (ch) {
            __syncthreads();
            stageB(Wcat + (size_t)ch * 16384, Bs, wave, lane);
            __syncthreads();
        }
#pragma unroll
        for (int nt = 0; nt < 4; ++nt) {
            f32x4 c = {0.f, 0.f, 0.f, 0.f};
#pragma unroll
            for (int ks = 0; ks < 8; ++ks)
                c = __builtin_amdgcn_mfma_f32_16x16x32_bf16(
                    a[ks], *(const short8*)(Bs + ((nt * 8 + ks) * 64 + lane) * 16), c, 0, 0, 0);
            acc[ch * 4 + nt] = c;
        }
    }
    float ssq[4] = {0.f, 0.f, 0.f, 0.f};
#pragma unroll
    for (int i = 0; i < 8; ++i) {
        float b = bias[i * 16 + col];
#pragma unroll
        for (int r = 0; r < 4; ++r) {
            acc[i][r] += b;
            ssq[r] += acc[i][r] * acc[i][r];
        }
    }
#pragma unroll
    for (int off = 1; off < 16; off <<= 1)
#pragma unroll
        for (int r = 0; r < 4; ++r) ssq[r] += __shfl_xor(ssq[r], off);
    float rn[4], p0[4] = {0.f,0.f,0.f,0.f}, p1[4] = {0.f,0.f,0.f,0.f};
#pragma unroll
    for (int r = 0; r < 4; ++r) rn[r] = 1.0f / fmaxf(sqrtf(ssq[r]), 1e-12f);
#pragma unroll
    for (int i = 0; i < 8; ++i) {
        int chan = i * 16 + col;
        float w0 = Wlin2[chan], w1 = Wlin2[128 + chan];
#pragma unroll
        for (int r = 0; r < 4; ++r) {
            float yv = acc[i][r] * rn[r];
            acc[i][r] = yv;
            p0[r] += yv * w0;
            p1[r] += yv * w1;
        }
    }
#pragma unroll
    for (int off = 1; off < 16; off <<= 1)
#pragma unroll
        for (int r = 0; r < 4; ++r) { p0[r] += __shfl_xor(p0[r], off); p1[r] += __shfl_xor(p1[r], off); }
#pragma unroll
    for (int r = 0; r < 4; ++r) {
        int node = m0 + wave * 16 + kg * 4 + r;
        if (node < NN) {
#pragma unroll
            for (int i = 0; i < 8; ++i)
                yout[(size_t)node * 128 + i * 16 + col] = acc[i][r];
            if (col == 0) {
                float l0 = p0[r] + blin2[0], l1 = p1[r] + blin2[1];
                float mx = fmaxf(l0, l1);
                float e0 = expf(l0 - mx), e1 = expf(l1 - mx);
                float inv = 1.0f / (e0 + e1);
                probs[(size_t)node * 2 + 0] = e0 * inv;
                probs[(size_t)node * 2 + 1] = e1 * inv;
            }
        }
    }
}

extern "C" void kernel_launch(void* const* d_in, const int* in_sizes, int n_in,
                              void* d_out, int out_size, void* d_ws, size_t ws_size,
                              hipStream_t stream) {
    const float* x     = (const float*)d_in[0];
    const int*   ei    = (const int*)d_in[1];
    const int*   src   = ei;
    const int*   tgt   = ei + NE;
    const float* W1l   = (const float*)d_in[2];
    const float* b1l   = (const float*)d_in[3];
    const float* W1r   = (const float*)d_in[4];
    const float* Wlin  = (const float*)d_in[5];
    const float* blin  = (const float*)d_in[6];
    const float* W2l   = (const float*)d_in[7];
    const float* b2l   = (const float*)d_in[8];
    const float* W2r   = (const float*)d_in[9];
    const float* Wlin2 = (const float*)d_in[10];
    const float* blin2 = (const float*)d_in[11];

    float* probs = (float*)d_out;              // [N,2]
    float* y     = (float*)d_out + 2 * NN;     // [N,128]

    // ws layout
    int*    bcursor   = (int*)d_ws;                     // NBK (zeroed each call)
    int*    rowstart  = bcursor + NBK;                  // NN
    int*    rowend    = rowstart + NN;                  // NN
    uint*   brec      = (uint*)(rowend + NN);           // NBK*CAP
    int*    sortedSrc = (int*)(brec + (size_t)NBK * CAP); // NBK*CAP
    ushort* Wcat1     = (ushort*)(sortedSrc + (size_t)NBK * CAP); // 256*256 (frag-major)
    ushort* Wlinb     = Wcat1 + 65536;                  // 128*256 (frag-major)
    ushort* Wcat2     = Wlinb + 32768;                  // 128*256 (frag-major)
    ushort* xbf       = Wcat2 + 32768;                  // N*128 bf16
    ushort* hr        = xbf + (size_t)NN * 128;         // N*128 bf16
    ushort* mean      = hr + (size_t)NN * 128;          // N*128 bf16
    uchar*  x8        = (uchar*)(mean + (size_t)NN * 128); // N*128 fp8
    uchar*  hr8       = x8 + (size_t)NN * 128;          // N*128 fp8

    const int NEB = (NE + EPB - 1) / EPB;               // 196 edge blocks

    hipMemsetAsync(bcursor, 0, sizeof(int) * NBK, stream);

    prep_scatter<<<PREPB + NEB, 256, 0, stream>>>(W1l, W1r, Wlin, W2l, W2r, x,
                                                  src, tgt,
                                                  Wcat1, Wlinb, Wcat2, xbf, x8,
                                                  bcursor, brec);

    bucket_to_csr<<<NBK, 256, 0, stream>>>(brec, bcursor, rowstart, rowend, sortedSrc);

    gather_mean8<<<(NN + 3) / 4, 256, 0, stream>>>(x8, rowstart, rowend, sortedSrc, mean);
    conv1lin_mfma<<<(NN + 63) / 64, 256, 0, stream>>>(mean, xbf, Wcat1, b1l,
                                                      Wlinb, blin, hr);
    cvt8<<<NN * 128 / 8 / 256, 256, 0, stream>>>(hr, hr8);
    gather_mean8<<<(NN + 3) / 4, 256, 0, stream>>>(hr8, rowstart, rowend, sortedSrc, mean);
    conv2_mfma<<<(NN + 63) / 64, 256, 0, stream>>>(mean, hr, Wcat2, b2l,
                                                   Wlin2, blin2, probs, y);
}

// Round 24
// 261.887 us; speedup vs baseline: 1.0419x; 1.0419x over previous
//
#include <hip/hip_runtime.h>
#include <hip/hip_bf16.h>
#include <hip/hip_fp8.h>

#define NN   100000
#define NE   1600000
#define NBK  196      // ceil(NN/512) buckets
#define BSH  9        // 512 nodes per bucket
#define EPB  8192     // edges per scatter block
#define CAP  9216     // padded capacity per bucket (mean 8163 + ~11 sigma)

typedef __attribute__((ext_vector_type(8))) short short8;
typedef __attribute__((ext_vector_type(4))) float f32x4;
typedef __attribute__((address_space(3))) uint  lds_uint;
typedef __attribute__((address_space(1))) const uint glb_uint;

__device__ __forceinline__ ushort f2bf(float f) {
    union { float f; uint u; } v; v.f = f;
    uint u = v.u;
    return (ushort)((u + 0x7FFFu + ((u >> 16) & 1u)) >> 16);
}
__device__ __forceinline__ float bf2f(uint b) {
    union { uint u; float f; } v; v.u = b << 16;
    return v.f;
}
__device__ __forceinline__ float fp8f(uint byte) {
    __hip_fp8_e4m3 t; t.__x = (__hip_fp8_storage_t)(byte & 0xffu);
    return (float)t;
}
__device__ __forceinline__ uint f2fp8(float f) {
    __hip_fp8_e4m3 t(f);
    return (uint)t.__x;
}
// XOR-swizzle for 512B-stride LDS rows (guide G4) — used for h buffer only
__device__ __forceinline__ int swz(int off) { return off ^ (((off >> 9) & 7) << 4); }

// async global->LDS copy of a 32KB fragment-major chunk (2048 x 16B)
__device__ __forceinline__ void stageB(const ushort* __restrict__ W, char* Bs,
                                       int wave, int lane) {
#pragma unroll
    for (int k = 0; k < 8; ++k) {
        int base = k * 256 + wave * 64;          // 16B-unit index, wave-uniform
        __builtin_amdgcn_global_load_lds(
            (glb_uint*)(W + (size_t)(base + lane) * 8),
            (lds_uint*)(Bs + base * 16), 16, 0, 0);
    }
}

// ------- bucket scatter: block-local order by bucket, coalesced runs -------
__global__ __launch_bounds__(256) void bucket_scatter(const int* __restrict__ src,
                                                      const int* __restrict__ tgt,
                                                      int* __restrict__ bcursor,
                                                      uint* __restrict__ brec) {
    __shared__ int lh[NBK + 1];
    __shared__ int lcur[NBK];
    __shared__ int lbase[NBK];
    __shared__ uint lrec[EPB];
    __shared__ int ws[4];
    int tid = threadIdx.x;
    for (int i = tid; i < NBK; i += 256) lh[i] = 0;
    __syncthreads();
    int base4 = blockIdx.x * (EPB / 4);
#pragma unroll
    for (int k = 0; k < 8; ++k) {
        int i4 = base4 + k * 256 + tid;
        if (i4 < NE / 4) {
            int4 t = ((const int4*)tgt)[i4];
            atomicAdd(&lh[t.x >> BSH], 1);
            atomicAdd(&lh[t.y >> BSH], 1);
            atomicAdd(&lh[t.z >> BSH], 1);
            atomicAdd(&lh[t.w >> BSH], 1);
        }
    }
    __syncthreads();
    int v = (tid < NBK) ? lh[tid] : 0;
    int lane = tid & 63, wid = tid >> 6;
    int inc = v;
#pragma unroll
    for (int off = 1; off < 64; off <<= 1) {
        int u = __shfl_up(inc, off);
        if (lane >= off) inc += u;
    }
    if (lane == 63) ws[wid] = inc;
    __syncthreads();
    int woff = 0;
    for (int w = 0; w < wid; ++w) woff += ws[w];
    int ex = woff + inc - v;
    int nval = min(EPB, NE - blockIdx.x * EPB);
    if (tid < NBK) {
        lh[tid] = ex;
        lcur[tid] = ex;
        lbase[tid] = v ? atomicAdd(&bcursor[tid], v) : 0;
    }
    if (tid == 0) lh[NBK] = nval;
    __syncthreads();
#pragma unroll
    for (int k = 0; k < 8; ++k) {
        int i4 = base4 + k * 256 + tid;
        if (i4 < NE / 4) {
            int4 t = ((const int4*)tgt)[i4];
            int4 s = ((const int4*)src)[i4];
            int p;
            p = atomicAdd(&lcur[t.x >> BSH], 1); lrec[p] = ((uint)s.x << BSH) | (uint)(t.x & 511);
            p = atomicAdd(&lcur[t.y >> BSH], 1); lrec[p] = ((uint)s.y << BSH) | (uint)(t.y & 511);
            p = atomicAdd(&lcur[t.z >> BSH], 1); lrec[p] = ((uint)s.z << BSH) | (uint)(t.z & 511);
            p = atomicAdd(&lcur[t.w >> BSH], 1); lrec[p] = ((uint)s.w << BSH) | (uint)(t.w & 511);
        }
    }
    __syncthreads();
    // write-out: contiguous 32-elem chunk per thread, monotone bucket pointer
    {
        int i0 = tid * 32;
        int lo = 0, hi = NBK;
        while (hi - lo > 1) { int mid = (lo + hi) >> 1; if (lh[mid] <= i0) lo = mid; else hi = mid; }
#pragma unroll 4
        for (int k = 0; k < 32; ++k) {
            int i = i0 + k;
            if (i >= nval) break;
            while (lh[lo + 1] <= i) ++lo;
            brec[lbase[lo] + (i - lh[lo])] = lrec[i];
        }
    }
}

// ------- bucket -> CSR (padded regions; writes rowstart + rowend) -------
__global__ __launch_bounds__(256) void bucket_to_csr(const uint* __restrict__ brec,
                                                     const int* __restrict__ bcursor,
                                                     int* __restrict__ rowstart,
                                                     int* __restrict__ rowend,
                                                     int* __restrict__ sortedSrc) {
    __shared__ int cnt[512];
    __shared__ int cur[512];
    __shared__ int srt[CAP];
    __shared__ int ws[4];
    int b = blockIdx.x;
    int beg = b * CAP;
    int len = min(bcursor[b] - beg, CAP);
    int end = beg + len;
    int n0 = b << BSH;
    int ncnt = min(512, NN - n0);
    int tid = threadIdx.x;
    cnt[tid] = 0; cnt[tid + 256] = 0;
    __syncthreads();
    for (int i = beg + tid; i < end; i += 256)
        atomicAdd(&cnt[brec[i] & 511u], 1);
    __syncthreads();
    int c0 = cnt[2 * tid], c1 = cnt[2 * tid + 1];
    int s = c0 + c1;
    int lane = tid & 63, wid = tid >> 6;
    int inc = s;
#pragma unroll
    for (int off = 1; off < 64; off <<= 1) {
        int u = __shfl_up(inc, off);
        if (lane >= off) inc += u;
    }
    if (lane == 63) ws[wid] = inc;
    __syncthreads();
    int woff = 0;
    for (int w = 0; w < wid; ++w) woff += ws[w];
    int ex = woff + inc - s;
    cur[2 * tid] = ex; cur[2 * tid + 1] = ex + c0;
    if (2 * tid < ncnt) {
        rowstart[n0 + 2 * tid] = beg + ex;
        rowend[n0 + 2 * tid]   = beg + ex + c0;
    }
    if (2 * tid + 1 < ncnt) {
        rowstart[n0 + 2 * tid + 1] = beg + ex + c0;
        rowend[n0 + 2 * tid + 1]   = beg + ex + c0 + c1;
    }
    __syncthreads();
    for (int i = beg + tid; i < end; i += 256) {
        uint r = brec[i];
        int p = atomicAdd(&cur[r & 511u], 1);
        srt[p] = (int)(r >> BSH);
    }
    __syncthreads();
    // vectorized copy-out: beg = b*CAP is 16B-aligned
    {
        int len4 = len >> 2;
        int4* dst4 = (int4*)&sortedSrc[beg];
        const int4* src4 = (const int4*)srt;
        for (int i = tid; i < len4; i += 256)
            dst4[i] = src4[i];
        for (int i = (len4 << 2) + tid; i < len; i += 256)
            sortedSrc[beg + i] = srt[i];
    }
}

// --- gather mean (fp8): wave/node, quarter-wave/edge, 8B/lane, unroll-4 ---
__global__ __launch_bounds__(256) void gather_mean8(const uchar* __restrict__ t8,
                                                    const int* __restrict__ rowstart,
                                                    const int* __restrict__ rowend,
                                                    const int* __restrict__ sortedSrc,
                                                    ushort* __restrict__ mean) {
    int node = blockIdx.x * 4 + (threadIdx.x >> 6);
    if (node >= NN) return;
    int lane = threadIdx.x & 63;
    int q = lane >> 4, l = lane & 15;
    int beg = rowstart[node], end = rowend[node];
    float a0 = 0.f, a1 = 0.f, a2 = 0.f, a3 = 0.f;
    float a4 = 0.f, a5 = 0.f, a6 = 0.f, a7 = 0.f;
    float b0 = 0.f, b1 = 0.f, b2 = 0.f, b3 = 0.f;
    float b4 = 0.f, b5 = 0.f, b6 = 0.f, b7 = 0.f;
#define ACCA(v) { a0 += fp8f(v.x);       a1 += fp8f(v.x >> 8); \
                  a2 += fp8f(v.x >> 16); a3 += fp8f(v.x >> 24); \
                  a4 += fp8f(v.y);       a5 += fp8f(v.y >> 8); \
                  a6 += fp8f(v.y >> 16); a7 += fp8f(v.y >> 24); }
#define ACCB(v) { b0 += fp8f(v.x);       b1 += fp8f(v.x >> 8); \
                  b2 += fp8f(v.x >> 16); b3 += fp8f(v.x >> 24); \
                  b4 += fp8f(v.y);       b5 += fp8f(v.y >> 8); \
                  b6 += fp8f(v.y >> 16); b7 += fp8f(v.y >> 24); }
    int i = beg + q;
    for (; i + 12 < end; i += 16) {
        int s0 = sortedSrc[i];
        int s1 = sortedSrc[i + 4];
        int s2 = sortedSrc[i + 8];
        int s3 = sortedSrc[i + 12];
        uint2 v0 = *(const uint2*)&t8[(size_t)s0 * 128 + l * 8];
        uint2 v1 = *(const uint2*)&t8[(size_t)s1 * 128 + l * 8];
        uint2 v2 = *(const uint2*)&t8[(size_t)s2 * 128 + l * 8];
        uint2 v3 = *(const uint2*)&t8[(size_t)s3 * 128 + l * 8];
        ACCA(v0) ACCB(v1) ACCA(v2) ACCB(v3)
    }
    for (; i < end; i += 4) {
        int s0 = sortedSrc[i];
        uint2 v0 = *(const uint2*)&t8[(size_t)s0 * 128 + l * 8];
        ACCA(v0)
    }
#undef ACCA
#undef ACCB
    a0 += b0; a1 += b1; a2 += b2; a3 += b3;
    a4 += b4; a5 += b5; a6 += b6; a7 += b7;
#define CMB(a) a += __shfl_xor(a, 32); a += __shfl_xor(a, 16);
    CMB(a0) CMB(a1) CMB(a2) CMB(a3) CMB(a4) CMB(a5) CMB(a6) CMB(a7)
#undef CMB
    if (lane < 16) {
        float id = 1.0f / fmaxf((float)(end - beg), 1.0f);
        ushort p[8];
        p[0] = f2bf(a0 * id); p[1] = f2bf(a1 * id);
        p[2] = f2bf(a2 * id); p[3] = f2bf(a3 * id);
        p[4] = f2bf(a4 * id); p[5] = f2bf(a5 * id);
        p[6] = f2bf(a6 * id); p[7] = f2bf(a7 * id);
        *(uint4*)&mean[(size_t)node * 128 + l * 8] = *(uint4*)p;
    }
}

// ---- prep_all: weights fp32->bf16 fragment-major + x->bf16/fp8 + bcursor ----
__global__ __launch_bounds__(256) void prep_all(const float* __restrict__ W1l,
                                                const float* __restrict__ W1r,
                                                const float* __restrict__ Wlin,
                                                const float* __restrict__ W2l,
                                                const float* __restrict__ W2r,
                                                const float* __restrict__ x,
                                                ushort* __restrict__ Wcat1,
                                                ushort* __restrict__ Wlinb,
                                                ushort* __restrict__ Wcat2,
                                                ushort* __restrict__ xbf,
                                                uchar* __restrict__ x8,
                                                int* __restrict__ bcursor) {
    int b = blockIdx.x, tid = threadIdx.x;
    if (b == 0 && tid < NBK) bcursor[tid] = tid * CAP;
    if (b < 512) {
        int i = b * 256 + tid;
        if (i < 65536) {               // Wcat1: 4 chunks (256 outputs, K=256)
            int e = i & 7, d = (i >> 3) & 63, g = (i >> 9) & 31, ch = i >> 14;
            int col = d & 15, kg = d >> 4, ks = g & 7, nt = g >> 3;
            int row = ch * 64 + nt * 16 + col;
            int k = ks * 32 + kg * 8 + e;
            float v = (k < 128) ? W1l[row * 128 + k] : W1r[row * 128 + k - 128];
            Wcat1[i] = f2bf(v);
        } else if (i < 98304) {        // Wlin: 2 chunks
            int j = i - 65536;
            int e = j & 7, d = (j >> 3) & 63, g = (j >> 9) & 31, ch = j >> 14;
            int col = d & 15, kg = d >> 4, ks = g & 7, nt = g >> 3;
            int row = ch * 64 + nt * 16 + col;
            int k = ks * 32 + kg * 8 + e;
            Wlinb[j] = f2bf(Wlin[row * 256 + k]);
        } else {                       // Wcat2: 2 chunks
            int j = i - 98304;
            int e = j & 7, d = (j >> 3) & 63, g = (j >> 9) & 31, ch = j >> 14;
            int col = d & 15, kg = d >> 4, ks = g & 7, nt = g >> 3;
            int row = ch * 64 + nt * 16 + col;
            int k = ks * 32 + kg * 8 + e;
            float v = (k < 128) ? W2l[row * 128 + k] : W2r[row * 128 + k - 128];
            Wcat2[j] = f2bf(v);
        }
    } else {
        int i = (b - 512) * 256 + tid;   // over NN*128/4 = 3.2M float4
        float4 v = ((const float4*)x)[i];
        ushort4 p;
        p.x = f2bf(v.x); p.y = f2bf(v.y); p.z = f2bf(v.z); p.w = f2bf(v.w);
        ((ushort4*)xbf)[i] = p;
        uint q = f2fp8(v.x) | (f2fp8(v.y) << 8) | (f2fp8(v.z) << 16) | (f2fp8(v.w) << 24);
        ((uint*)x8)[i] = q;
    }
}

// ---------------- hr bf16 -> fp8 (gather table only) ----------------
__global__ __launch_bounds__(256) void cvt8(const ushort* __restrict__ hr,
                                            uchar* __restrict__ hr8) {
    int i = blockIdx.x * 256 + threadIdx.x;   // over NN*128/8
    uint4 v = ((const uint4*)hr)[i];
    uint lo = f2fp8(bf2f(v.x & 0xffffu)) | (f2fp8(bf2f(v.x >> 16)) << 8) |
              (f2fp8(bf2f(v.y & 0xffffu)) << 16) | (f2fp8(bf2f(v.y >> 16)) << 24);
    uint hi = f2fp8(bf2f(v.z & 0xffffu)) | (f2fp8(bf2f(v.z >> 16)) << 8) |
              (f2fp8(bf2f(v.w & 0xffffu)) << 16) | (f2fp8(bf2f(v.w >> 16)) << 24);
    uint2 o; o.x = lo; o.y = hi;
    ((uint2*)hr8)[i] = o;
}

// --- conv1+linear fused: direct-global A, fragment-major B (gll),
//     As (32KB) used only for the h transpose; writes hr (bf16) ---
__global__ __launch_bounds__(256) void conv1lin_mfma(const ushort* __restrict__ mean,
                                                     const ushort* __restrict__ xbf,
                                                     const ushort* __restrict__ Wcat,
                                                     const float* __restrict__ bias1,
                                                     const ushort* __restrict__ Wlin,
                                                     const float* __restrict__ blin,
                                                     ushort* __restrict__ hr) {
    __shared__ char As[64 * 512];   // h buffer (swz layout)
    __shared__ char Bs[64 * 512];   // fragment-major weight chunk (32KB)
    int m0 = blockIdx.x * 64;
    int tid = threadIdx.x;
    int lane = tid & 63, wave = tid >> 6;
    int col = lane & 15, kg = lane >> 4;
    int mym = wave * 16 + col;
    int mm = min(m0 + mym, NN - 1);
    stageB(Wcat, Bs, wave, lane);
    short8 a[8];
#pragma unroll
    for (int ks = 0; ks < 4; ++ks)
        a[ks] = *(const short8*)&mean[(size_t)mm * 128 + ks * 32 + kg * 8];
#pragma unroll
    for (int ks = 4; ks < 8; ++ks)
        a[ks] = *(const short8*)&xbf[(size_t)mm * 128 + (ks - 4) * 32 + kg * 8];
    __syncthreads();                 // drains chunk-0 DMA + a-loads

    f32x4 acc[16];
    for (int ch = 0; ch < 4; ++ch) {       // 64-output fragment-major chunks
        if (ch) {
            __syncthreads();               // prior bq reads done before restage
            stageB(Wcat + (size_t)ch * 16384, Bs, wave, lane);
            __syncthreads();               // drain DMA
        }
#pragma unroll
        for (int nt = 0; nt < 4; ++nt) {
            f32x4 c = {0.f, 0.f, 0.f, 0.f};
#pragma unroll
            for (int ks = 0; ks < 8; ++ks)
                c = __builtin_amdgcn_mfma_f32_16x16x32_bf16(
                    a[ks], *(const short8*)(Bs + ((nt * 8 + ks) * 64 + lane) * 16), c, 0, 0, 0);
            acc[ch * 4 + nt] = c;
        }
    }
    // bias + l2norm  (chan for acc[i] = i*16 + col)
    float ssq[4] = {0.f, 0.f, 0.f, 0.f};
#pragma unroll
    for (int i = 0; i < 16; ++i) {
        float b = bias1[i * 16 + col];
#pragma unroll
        for (int r = 0; r < 4; ++r) {
            acc[i][r] += b;
            ssq[r] += acc[i][r] * acc[i][r];
        }
    }
#pragma unroll
    for (int off = 1; off < 16; off <<= 1)
#pragma unroll
        for (int r = 0; r < 4; ++r) ssq[r] += __shfl_xor(ssq[r], off);
    float rn[4];
#pragma unroll
    for (int r = 0; r < 4; ++r) rn[r] = 1.0f / fmaxf(sqrtf(ssq[r]), 1e-12f);
    // write normalized h (bf16) into As (own wave's rows only)
#pragma unroll
    for (int i = 0; i < 16; ++i) {
        int chan = i * 16 + col;
#pragma unroll
        for (int r = 0; r < 4; ++r)
            *(ushort*)(As + swz((wave * 16 + kg * 4 + r) * 512 + chan * 2)) = f2bf(acc[i][r] * rn[r]);
    }
    // second GEMM: hr = relu(h @ Wlin^T + blin); a2 rows self-owned (wave-local)
    short8 a2[8];
#pragma unroll
    for (int ks = 0; ks < 8; ++ks)
        a2[ks] = *(const short8*)(As + swz(mym * 512 + (ks * 32 + kg * 8) * 2));
    f32x4 acc2[8];
    for (int lc = 0; lc < 2; ++lc) {
        __syncthreads();                   // conv bq / prior reads done before restage
        stageB(Wlin + (size_t)lc * 16384, Bs, wave, lane);
        __syncthreads();
#pragma unroll
        for (int nt = 0; nt < 4; ++nt) {
            f32x4 c = {0.f, 0.f, 0.f, 0.f};
#pragma unroll
            for (int ks = 0; ks < 8; ++ks)
                c = __builtin_amdgcn_mfma_f32_16x16x32_bf16(
                    a2[ks], *(const short8*)(Bs + ((nt * 8 + ks) * 64 + lane) * 16), c, 0, 0, 0);
            acc2[lc * 4 + nt] = c;
        }
    }
#pragma unroll
    for (int i = 0; i < 8; ++i) {
        int chan = i * 16 + col;
        float b = blin[chan];
#pragma unroll
        for (int r = 0; r < 4; ++r) {
            int node = m0 + wave * 16 + kg * 4 + r;
            if (node < NN)
                hr[(size_t)node * 128 + chan] = f2bf(fmaxf(acc2[i][r] + b, 0.f));
        }
    }
}

// --- conv2 + linear2 + softmax: direct-global A (self-term bf16 from hr),
//     Bs-only LDS (32KB) ---
__global__ __launch_bounds__(256) void conv2_mfma(const ushort* __restrict__ mean,
                                                  const ushort* __restrict__ hr,
                                                  const ushort* __restrict__ Wcat,
                                                  const float* __restrict__ bias,
                                                  const float* __restrict__ Wlin2,
                                                  const float* __restrict__ blin2,
                                                  float* __restrict__ probs,
                                                  float* __restrict__ yout) {
    __shared__ char Bs[64 * 512];   // only LDS: 32KB weight chunk
    int m0 = blockIdx.x * 64;
    int tid = threadIdx.x;
    int lane = tid & 63, wave = tid >> 6;
    int col = lane & 15, kg = lane >> 4;
    int mym = wave * 16 + col;
    int mm = min(m0 + mym, NN - 1);
    stageB(Wcat, Bs, wave, lane);
    short8 a[8];
#pragma unroll
    for (int ks = 0; ks < 4; ++ks)
        a[ks] = *(const short8*)&mean[(size_t)mm * 128 + ks * 32 + kg * 8];
#pragma unroll
    for (int ks = 4; ks < 8; ++ks)
        a[ks] = *(const short8*)&hr[(size_t)mm * 128 + (ks - 4) * 32 + kg * 8];
    __syncthreads();

    f32x4 acc[8];
    for (int ch = 0; ch < 2; ++ch) {
        if (ch) {
            __syncthreads();
            stageB(Wcat + (size_t)ch * 16384, Bs, wave, lane);
            __syncthreads();
        }
#pragma unroll
        for (int nt = 0; nt < 4; ++nt) {
            f32x4 c = {0.f, 0.f, 0.f, 0.f};
#pragma unroll
            for (int ks = 0; ks < 8; ++ks)
                c = __builtin_amdgcn_mfma_f32_16x16x32_bf16(
                    a[ks], *(const short8*)(Bs + ((nt * 8 + ks) * 64 + lane) * 16), c, 0, 0, 0);
            acc[ch * 4 + nt] = c;
        }
    }
    float ssq[4] = {0.f, 0.f, 0.f, 0.f};
#pragma unroll
    for (int i = 0; i < 8; ++i) {
        float b = bias[i * 16 + col];
#pragma unroll
        for (int r = 0; r < 4; ++r) {
            acc[i][r] += b;
            ssq[r] += acc[i][r] * acc[i][r];
        }
    }
#pragma unroll
    for (int off = 1; off < 16; off <<= 1)
#pragma unroll
        for (int r = 0; r < 4; ++r) ssq[r] += __shfl_xor(ssq[r], off);
    float rn[4], p0[4] = {0.f,0.f,0.f,0.f}, p1[4] = {0.f,0.f,0.f,0.f};
#pragma unroll
    for (int r = 0; r < 4; ++r) rn[r] = 1.0f / fmaxf(sqrtf(ssq[r]), 1e-12f);
#pragma unroll
    for (int i = 0; i < 8; ++i) {
        int chan = i * 16 + col;
        float w0 = Wlin2[chan], w1 = Wlin2[128 + chan];
#pragma unroll
        for (int r = 0; r < 4; ++r) {
            float yv = acc[i][r] * rn[r];
            acc[i][r] = yv;
            p0[r] += yv * w0;
            p1[r] += yv * w1;
        }
    }
#pragma unroll
    for (int off = 1; off < 16; off <<= 1)
#pragma unroll
        for (int r = 0; r < 4; ++r) { p0[r] += __shfl_xor(p0[r], off); p1[r] += __shfl_xor(p1[r], off); }
#pragma unroll
    for (int r = 0; r < 4; ++r) {
        int node = m0 + wave * 16 + kg * 4 + r;
        if (node < NN) {
#pragma unroll
            for (int i = 0; i < 8; ++i)
                yout[(size_t)node * 128 + i * 16 + col] = acc[i][r];
            if (col == 0) {
                float l0 = p0[r] + blin2[0], l1 = p1[r] + blin2[1];
                float mx = fmaxf(l0, l1);
                float e0 = expf(l0 - mx), e1 = expf(l1 - mx);
                float inv = 1.0f / (e0 + e1);
                probs[(size_t)node * 2 + 0] = e0 * inv;
                probs[(size_t)node * 2 + 1] = e1 * inv;
            }
        }
    }
}

extern "C" void kernel_launch(void* const* d_in, const int* in_sizes, int n_in,
                              void* d_out, int out_size, void* d_ws, size_t ws_size,
                              hipStream_t stream) {
    const float* x     = (const float*)d_in[0];
    const int*   ei    = (const int*)d_in[1];
    const int*   src   = ei;
    const int*   tgt   = ei + NE;
    const float* W1l   = (const float*)d_in[2];
    const float* b1l   = (const float*)d_in[3];
    const float* W1r   = (const float*)d_in[4];
    const float* Wlin  = (const float*)d_in[5];
    const float* blin  = (const float*)d_in[6];
    const float* W2l   = (const float*)d_in[7];
    const float* b2l   = (const float*)d_in[8];
    const float* W2r   = (const float*)d_in[9];
    const float* Wlin2 = (const float*)d_in[10];
    const float* blin2 = (const float*)d_in[11];

    float* probs = (float*)d_out;              // [N,2]
    float* y     = (float*)d_out + 2 * NN;     // [N,128]

    // ws layout
    int*    bcursor   = (int*)d_ws;                     // NBK
    int*    rowstart  = bcursor + NBK;                  // NN
    int*    rowend    = rowstart + NN;                  // NN
    uint*   brec      = (uint*)(rowend + NN);           // NBK*CAP
    int*    sortedSrc = (int*)(brec + (size_t)NBK * CAP); // NBK*CAP
    ushort* Wcat1     = (ushort*)(sortedSrc + (size_t)NBK * CAP); // 256*256 (frag-major)
    ushort* Wlinb     = Wcat1 + 65536;                  // 128*256 (frag-major)
    ushort* Wcat2     = Wlinb + 32768;                  // 128*256 (frag-major)
    ushort* xbf       = Wcat2 + 32768;                  // N*128 bf16
    ushort* hr        = xbf + (size_t)NN * 128;         // N*128 bf16
    ushort* mean      = hr + (size_t)NN * 128;          // N*128 bf16
    uchar*  x8        = (uchar*)(mean + (size_t)NN * 128); // N*128 fp8
    uchar*  hr8       = x8 + (size_t)NN * 128;          // N*128 fp8

    const int NEB = (NE + EPB - 1) / EPB;               // 196 edge blocks

    prep_all<<<512 + NN * 32 / 256, 256, 0, stream>>>(W1l, W1r, Wlin, W2l, W2r, x,
                                                      Wcat1, Wlinb, Wcat2,
                                                      xbf, x8, bcursor);

    bucket_scatter<<<NEB, 256, 0, stream>>>(src, tgt, bcursor, brec);
    bucket_to_csr<<<NBK, 256, 0, stream>>>(brec, bcursor, rowstart, rowend, sortedSrc);

    gather_mean8<<<(NN + 3) / 4, 256, 0, stream>>>(x8, rowstart, rowend, sortedSrc, mean);
    conv1lin_mfma<<<(NN + 63) / 64, 256, 0, stream>>>(mean, xbf, Wcat1, b1l,
                                                      Wlinb, blin, hr);
    cvt8<<<NN * 128 / 8 / 256, 256, 0, stream>>>(hr, hr8);
    gather_mean8<<<(NN + 3) / 4, 256, 0, stream>>>(hr8, rowstart, rowend, sortedSrc, mean);
    conv2_mfma<<<(NN + 63) / 64, 256, 0, stream>>>(mean, hr, Wcat2, b2l,
                                                   Wlin2, blin2, probs, y);
}